// Round 15
// baseline (471.213 us; speedup 1.0000x reference)
//
#include <hip/hip_runtime.h>
#include <hip/hip_bf16.h>
#include <stdint.h>

typedef __bf16 bf16;
typedef float f32x4 __attribute__((ext_vector_type(4)));
typedef bf16 bf16x4 __attribute__((ext_vector_type(4)));
typedef bf16 bf16x8 __attribute__((ext_vector_type(8)));

#define DEV __device__ __forceinline__

DEV void gload16(const void* g, void* l) {
  __builtin_amdgcn_global_load_lds((const __attribute__((address_space(1))) void*)g,
                                   (__attribute__((address_space(3))) void*)l, 16, 0, 0);
}

DEV f32x4 mfma16(bf16x8 a, bf16x8 b, f32x4 c) {
  return __builtin_amdgcn_mfma_f32_16x16x32_bf16(a, b, c, 0, 0, 0);
}

#if __has_builtin(__builtin_amdgcn_exp2f)
DEV float EXP2F(float x) { return __builtin_amdgcn_exp2f(x); }
#else
DEV float EXP2F(float x) { return exp2f(x); }
#endif

static constexpr int Bn = 4, Sn = 2048, Hn = 16, Dn = 128, En = 2048, Mn = 8192;

// ---------------- fused prep: X fp32->bf16 + 4x W transpose ----------------
__global__ void prep(const float* __restrict__ X, bf16* __restrict__ Xb,
                     const float* __restrict__ Wq, const float* __restrict__ Wk,
                     const float* __restrict__ Wv, const float* __restrict__ Wo,
                     bf16* __restrict__ Wqt, bf16* __restrict__ Wkt,
                     bf16* __restrict__ Wvt, bf16* __restrict__ Wot, int n8) {
  __shared__ bf16 t[64][65];
  const int bid = blockIdx.x;
  if (bid < 2048) {
    int i = bid * 256 + threadIdx.x;
    const int stride = 2048 * 256;
    for (int idx = i; idx < n8; idx += stride) {
      const float4* p = (const float4*)(X + (size_t)idx * 8);
      float4 a = p[0], b = p[1];
      bf16x8 o;
      o[0]=(bf16)a.x; o[1]=(bf16)a.y; o[2]=(bf16)a.z; o[3]=(bf16)a.w;
      o[4]=(bf16)b.x; o[5]=(bf16)b.y; o[6]=(bf16)b.z; o[7]=(bf16)b.w;
      *(bf16x8*)(Xb + (size_t)idx * 8) = o;
    }
    return;
  }
  const int q = bid - 2048;
  const int mtx = q >> 10, within = q & 1023;
  const float* W = (mtx == 0) ? Wq : (mtx == 1) ? Wk : (mtx == 2) ? Wv : Wo;
  bf16* Wt = (mtx == 0) ? Wqt : (mtx == 1) ? Wkt : (mtx == 2) ? Wvt : Wot;
  int tx = threadIdx.x & 15, ty = threadIdx.x >> 4;
  int c0 = (within & 31) * 64, r0 = (within >> 5) * 64;
  #pragma unroll
  for (int i = 0; i < 4; ++i) {
    int r = i * 16 + ty;
    float4 v = *(const float4*)&W[(size_t)(r0 + r) * En + c0 + tx * 4];
    t[r][tx*4+0] = (bf16)v.x; t[r][tx*4+1] = (bf16)v.y;
    t[r][tx*4+2] = (bf16)v.z; t[r][tx*4+3] = (bf16)v.w;
  }
  __syncthreads();
  #pragma unroll
  for (int i = 0; i < 4; ++i) {
    int c = i * 16 + ty;
    bf16x4 o;
    #pragma unroll
    for (int j = 0; j < 4; ++j) o[j] = t[tx*4+j][c];
    *(bf16x4*)&Wt[(size_t)(c0 + c) * En + r0 + tx * 4] = o;
  }
}

// ---------------- 256x256 GEMM, 16 waves, BK=32 quad-buffer (r15) --------
// r12 ledger residual: ~900cyc/tile end-of-tile vmcnt(0) drain (DMA writes
// queue behind LDS reads on the shared port; depth-1 pipeline forces full
// drain each tile). r15: BK=32 tiles (32KB) -> QUAD-buffered LDS (4x32KB),
// stage tile t+2 at tile t, gate with vmcnt(2): per-wave FIFO retires exactly
// t+1's 2 stage ops; t+2's 2 stay in flight ACROSS the barrier (T4 counted
// vmcnt). Loads get ~2 tiles (~4000cyc) slack -> write-port contention
// hidden. Body = r12's kh-half verbatim (64B rows, same verified swizzle,
// same registers). Buffer rotation: tile t reads buf[t&3], stages buf[(t+2)&3];
// buf[(t+3)&3] is the one freed at t-1's barrier.
#define STAGE_A(KTN) gload16( \
    A + (size_t)(mbase + (tid >> 2)) * K + (KTN) * 32 \
      + (((tid & 3) ^ ((tid >> 3) & 3)) * 8), \
    smem + (((KTN) & 3) << 14) + tid * 16)
#define STAGE_B(KTN) gload16( \
    Bt + (size_t)(nbase + (tid >> 2)) * K + (KTN) * 32 \
      + (((tid & 3) ^ ((tid >> 3) & 3)) * 8), \
    smem + 65536 + (((KTN) & 3) << 14) + tid * 16)

template<int OUT_MODE>
__global__ __launch_bounds__(1024, 2) void gemm256(
    const bf16* __restrict__ A, const bf16* __restrict__ Bt,
    const float* __restrict__ b0, const float* __restrict__ b1,
    const float* __restrict__ b2, void* __restrict__ Cout,
    bf16* __restrict__ Vout,
    int M, int N, int K, int sbx, int sby)
{
  __shared__ __align__(16) uint8_t smem[131072];   // A: 4x16KB, B: 4x16KB
  const int tid = threadIdx.x, lane = tid & 63, w = tid >> 6;   // w in [0,16)
  const int wm = w >> 2, wn = w & 3;                            // 4M x 4N waves
  const int g = lane >> 4, lr = lane & 15;
  const int gx = (g ^ ((lr >> 1) & 3)) << 4;   // swizzled 16B-chunk offset
  // 2D XCD super-tiling (r10)
  const int lid = blockIdx.x;
  const int xcd = lid & 7, i = lid >> 3;
  const int bx = (xcd & 1) * sbx + (i % sbx);
  const int by = (xcd >> 1) * sby + (i / sbx);
  const int mbase = by * 256, nbase = bx * 256;

  f32x4 acc[4][4] = {};

  // prologue: stage tiles 0 and 1; retire tile 0 (vmcnt(2): keep tile 1's
  // 2 ops in flight), join.
  STAGE_A(0); STAGE_B(0);
  STAGE_A(1); STAGE_B(1);
  asm volatile("s_waitcnt vmcnt(2)" ::: "memory");
  __builtin_amdgcn_s_barrier();

  const int NKT = K >> 5;   // BK = 32
  for (int kt = 0; kt < NKT; ++kt) {
    uint8_t* Acur = smem + ((kt & 3) << 14);
    uint8_t* Bcur = smem + 65536 + ((kt & 3) << 14);
    const bool deep = (kt + 2 < NKT);

    // issue stage for tile t+2 into the buffer freed at t-1's barrier
    if (deep) { STAGE_A(kt + 2); STAGE_B(kt + 2); }

    // frag reads + MFMA (r12 kh-half body; compiler emits precise lgkmcnt)
    bf16x8 af[4], bfv[4];
    #pragma unroll
    for (int mf = 0; mf < 4; ++mf)
      af[mf] = *(const bf16x8*)(Acur + (wm * 64 + mf * 16 + lr) * 64 + gx);
    #pragma unroll
    for (int j = 0; j < 4; ++j)
      bfv[j] = *(const bf16x8*)(Bcur + (wn * 64 + j * 16 + lr) * 64 + gx);
    __builtin_amdgcn_s_setprio(1);
    #pragma unroll
    for (int mf = 0; mf < 4; ++mf)
      #pragma unroll
      for (int j = 0; j < 4; ++j)
        acc[mf][j] = mfma16(af[mf], bfv[j], acc[mf][j]);
    __builtin_amdgcn_s_setprio(0);

    // gate: tile t+1's stages must be retired (ours: FIFO => vmcnt(2) with
    // t+2 in flight; vmcnt(0) when nothing deeper). Barrier publishes.
    if (deep) { asm volatile("s_waitcnt vmcnt(2)" ::: "memory"); }
    else      { asm volatile("s_waitcnt vmcnt(0)" ::: "memory"); }
    __builtin_amdgcn_s_barrier();
  }

  // ---- epilogue (per-wave output block 64x64 at wm,wn) ----
  if constexpr (OUT_MODE == 0) {
    int tsel = nbase >> 11;
    if (tsel == 2) {
      #pragma unroll
      for (int j = 0; j < 4; ++j) {
        int nn = (nbase + wn * 64 + j * 16 + lr) & 2047;
        int h = nn >> 7, d = nn & 127;
        float bv = b2[nn];
        #pragma unroll
        for (int mf = 0; mf < 4; ++mf) {
          int m0 = mbase + wm * 64 + mf * 16 + g * 4;
          int b = m0 >> 11, s0 = m0 & 2047;
          bf16x4 o4;
          #pragma unroll
          for (int r = 0; r < 4; ++r) o4[r] = (bf16)(acc[mf][j][r] + bv);
          *(bf16x4*)&Vout[((size_t)(b * Hn + h) * Dn + d) * Sn + s0] = o4;
        }
      }
    } else {
      const float* bsel = (tsel == 0) ? b0 : b1;
      #pragma unroll
      for (int j = 0; j < 4; ++j) {
        int n = nbase + wn * 64 + j * 16 + lr;
        int nn = n & 2047;
        float bv = bsel[nn];
        int h = nn >> 7, d = nn & 127;
        #pragma unroll
        for (int mf = 0; mf < 4; ++mf) {
          #pragma unroll
          for (int r = 0; r < 4; ++r) {
            int m = mbase + wm * 64 + mf * 16 + g * 4 + r;
            int b = m >> 11, s = m & 2047;
            ((bf16*)Cout)[(size_t)tsel * ((size_t)Mn * En) +
                          ((size_t)(b * Hn + h) * Sn + s) * Dn + d] = (bf16)(acc[mf][j][r] + bv);
          }
        }
      }
    }
  } else {
    #pragma unroll
    for (int j = 0; j < 4; ++j) {
      int n = nbase + wn * 64 + j * 16 + lr;
      float bv = b0[n];
      #pragma unroll
      for (int mf = 0; mf < 4; ++mf) {
        #pragma unroll
        for (int r = 0; r < 4; ++r) {
          int m = mbase + wm * 64 + mf * 16 + g * 4 + r;
          ((float*)Cout)[(size_t)m * N + n] = acc[mf][j][r] + bv;
        }
      }
    }
  }
}

// ---------------- Flash attention (r9-identical, best-verified) ----------
__global__ __launch_bounds__(512, 2) void attn(
    const bf16* __restrict__ Q, const bf16* __restrict__ K,
    const bf16* __restrict__ Vt, bf16* __restrict__ O)
{
  __shared__ __align__(16) uint8_t smem[65536];
  const int tid = threadIdx.x, lane = tid & 63, w = tid >> 6;
  const int g = lane >> 4, lr = lane & 15;
  const int lid = blockIdx.x;
  const int xcd = lid & 7, j = lid >> 3;
  const int bh = xcd * 8 + (j >> 3);
  const int q0 = (j & 7) * 256;
  const size_t hoff = (size_t)bh * Sn * Dn;
  const bf16* Qh = Q + hoff;
  const bf16* Kh = K + hoff;
  const bf16* Vh = Vt + hoff;   // [D][S]
  const float SC2 = 0.12751744f; // 1/sqrt(128) * log2(e)

  #pragma unroll
  for (int it = 0; it < 8; ++it) {
    int cl = it * 512 + tid;
    int row = cl >> 4, cs = cl & 15;
    int cg = cs ^ (row & 7);
    gload16(Qh + (size_t)(q0 + row) * Dn + cg * 8, smem + (it * 512 + (tid & ~63)) * 16);
  }
  __syncthreads();
  bf16x8 qf[2][4];
  #pragma unroll
  for (int nf = 0; nf < 2; ++nf)
    #pragma unroll
    for (int ks = 0; ks < 4; ++ks) {
      int row = w * 32 + nf * 16 + lr;
      qf[nf][ks] = *(const bf16x8*)(smem + row * 256 + (((ks * 4 + g) ^ (row & 7)) << 4));
    }
  __syncthreads();

  const int vd = tid >> 2, vq = tid & 3;
  const bf16* vrow = Vh + (size_t)vd * Sn + (vq >> 1) * 32 + (vq & 1) * 8;

  uint4 u0, u1;
  #pragma unroll
  for (int it = 0; it < 2; ++it) {
    int cl = it * 512 + tid;
    int row = cl >> 4, cs = cl & 15;
    int cg = cs ^ (row & 7);
    gload16(Kh + (size_t)row * Dn + cg * 8, smem + (it * 512 + (tid & ~63)) * 16);
  }
  { const uint4* vs = (const uint4*)vrow; u0 = vs[0]; u1 = vs[2]; }

  f32x4 o[2][8] = {};
  float m2[2] = { -__builtin_inff(), -__builtin_inff() };
  float lrun[2] = { 0.f, 0.f };

  for (int t = 0; t < 32; ++t) {
    const int cur = t & 1;
    uint8_t* Kcur = smem + (cur << 14);
    uint8_t* Knxt = smem + ((cur ^ 1) << 14);
    uint8_t* Vcur = smem + 32768 + (cur << 14);
    asm volatile("s_waitcnt vmcnt(0)" ::: "memory");
    {
      uint8_t* base = Vcur + vd * 128;
      const int sw = vd & 7;
      *(uint4*)(base + (((2 * vq + 0) ^ sw) << 4)) = make_uint4(u0.x, u0.y, u1.x, u1.y);
      *(uint4*)(base + (((2 * vq + 1) ^ sw) << 4)) = make_uint4(u0.z, u0.w, u1.z, u1.w);
    }
    if (t < 31) {
      const int kvn = (t + 1) * 64;
      #pragma unroll
      for (int it = 0; it < 2; ++it) {
        int cl = it * 512 + tid;
        int row = cl >> 4, cs = cl & 15;
        int cg = cs ^ (row & 7);
        gload16(Kh + (size_t)(kvn + row) * Dn + cg * 8,
                Knxt + (it * 512 + (tid & ~63)) * 16);
      }
      const uint4* vs = (const uint4*)(vrow + kvn);
      u0 = vs[0]; u1 = vs[2];
    }
    asm volatile("s_waitcnt lgkmcnt(0)" ::: "memory");
    asm volatile("s_barrier" ::: "memory");

    f32x4 sfr[2][4] = {};
    __builtin_amdgcn_s_setprio(1);
    #pragma unroll
    for (int ks = 0; ks < 4; ++ks) {
      #pragma unroll
      for (int mf = 0; mf < 4; ++mf) {
        int row = mf * 16 + lr;
        bf16x8 kf = *(const bf16x8*)(Kcur + row * 256 + (((ks * 4 + g) ^ (row & 7)) << 4));
        sfr[0][mf] = mfma16(kf, qf[0][ks], sfr[0][mf]);
        sfr[1][mf] = mfma16(kf, qf[1][ks], sfr[1][mf]);
      }
    }
    __builtin_amdgcn_s_setprio(0);

    bf16x8 pa[2][2];
    #pragma unroll
    for (int nf = 0; nf < 2; ++nf) {
      f32x4 a0, a1;
      #pragma unroll
      for (int r = 0; r < 4; ++r) a0[r] = fmaxf(sfr[nf][0][r], sfr[nf][1][r]);
      #pragma unroll
      for (int r = 0; r < 4; ++r) a1[r] = fmaxf(sfr[nf][2][r], sfr[nf][3][r]);
      #pragma unroll
      for (int r = 0; r < 4; ++r) a0[r] = fmaxf(a0[r], a1[r]);
      float mx = fmaxf(fmaxf(a0[0], a0[1]), fmaxf(a0[2], a0[3]));
      mx = fmaxf(mx, __shfl_xor(mx, 16));
      mx = fmaxf(mx, __shfl_xor(mx, 32));
      float pm2 = mx * SC2;
      if (__any(pm2 > m2[nf] + 8.f)) {
        float mnew = fmaxf(m2[nf], pm2);
        float fsc = EXP2F(m2[nf] - mnew);
        m2[nf] = mnew;
        lrun[nf] *= fsc;
        float fv[4];
        #pragma unroll
        for (int r = 0; r < 4; ++r) fv[r] = __shfl(fsc, g * 4 + r);
        #pragma unroll
        for (int df = 0; df < 8; ++df)
          #pragma unroll
          for (int r = 0; r < 4; ++r) o[nf][df][r] *= fv[r];
      }
      const float mc = m2[nf];
      f32x4 p[4];
      #pragma unroll
      for (int mf = 0; mf < 4; ++mf)
        #pragma unroll
        for (int r = 0; r < 4; ++r)
          p[mf][r] = EXP2F(__builtin_fmaf(sfr[nf][mf][r], SC2, -mc));
      f32x4 s0, s1;
      #pragma unroll
      for (int r = 0; r < 4; ++r) s0[r] = p[0][r] + p[1][r];
      #pragma unroll
      for (int r = 0; r < 4; ++r) s1[r] = p[2][r] + p[3][r];
      #pragma unroll
      for (int r = 0; r < 4; ++r) s0[r] += s1[r];
      float ps = (s0[0] + s0[1]) + (s0[2] + s0[3]);
      ps += __shfl_xor(ps, 16);
      ps += __shfl_xor(ps, 32);
      lrun[nf] += ps;
      #pragma unroll
      for (int ks = 0; ks < 2; ++ks) {
        bf16x8 tt;
        #pragma unroll
        for (int i = 0; i < 4; ++i) {
          tt[i]     = (bf16)p[2 * ks][i];
          tt[i + 4] = (bf16)p[2 * ks + 1][i];
        }
        pa[nf][ks] = tt;
      }
    }

    __builtin_amdgcn_s_setprio(1);
    #pragma unroll
    for (int ks = 0; ks < 2; ++ks) {
      #pragma unroll
      for (int df = 0; df < 8; ++df) {
        int row = df * 16 + lr;
        bf16x8 vf = *(const bf16x8*)(Vcur + row * 128 + (((ks * 4 + g) ^ (row & 7)) << 4));
        o[0][df] = mfma16(pa[0][ks], vf, o[0][df]);
        o[1][df] = mfma16(pa[1][ks], vf, o[1][df]);
      }
    }
    __builtin_amdgcn_s_setprio(0);
    asm volatile("s_barrier" ::: "memory");
  }

  const int b = bh >> 4, h = bh & 15;
  #pragma unroll
  for (int nf = 0; nf < 2; ++nf) {
    float inv = 1.f / lrun[nf];
    float iv[4];
    #pragma unroll
    for (int r = 0; r < 4; ++r) iv[r] = __shfl(inv, g * 4 + r);
    #pragma unroll
    for (int df = 0; df < 8; ++df) {
      #pragma unroll
      for (int r = 0; r < 4; ++r) {
        int qrow = q0 + w * 32 + nf * 16 + g * 4 + r;
        int d = df * 16 + lr;
        size_t m = (size_t)b * Sn + qrow;
        O[m * En + h * Dn + d] = (bf16)(o[nf][df][r] * iv[r]);
      }
    }
  }
}

// ---------------- host ----------------
extern "C" void kernel_launch(void* const* d_in, const int* in_sizes, int n_in,
                              void* d_out, int out_size, void* d_ws, size_t ws_size,
                              hipStream_t stream) {
  const float* X  = (const float*)d_in[0];
  const float* Wq = (const float*)d_in[1];
  const float* bq = (const float*)d_in[2];
  const float* Wk = (const float*)d_in[3];
  const float* bk = (const float*)d_in[4];
  const float* Wv = (const float*)d_in[5];
  const float* bv = (const float*)d_in[6];
  const float* Wo = (const float*)d_in[7];
  const float* bo = (const float*)d_in[8];

  bf16* ws = (bf16*)d_ws;
  const size_t szE = (size_t)Mn * En;
  const size_t szW = (size_t)En * En;
  bf16* Xb  = ws;
  bf16* Wqt = Xb + szE;      // Wqt/Wkt/Wvt contiguous => fused QKV B-matrix [6144][2048]
  bf16* Wkt = Wqt + szW;
  bf16* Wvt = Wkt + szW;
  bf16* Wot = Wvt + szW;
  bf16* Qb  = Wot + szW;     // Q/K contiguous for tsel addressing
  bf16* Kb  = Qb + szE;
  bf16* Vb  = Kb + szE;      // region reused for AO
  bf16* Vtp = Vb + szE;      // V written directly transposed [bh][D][S]
  bf16* AO  = Vb;

  prep<<<6144, 256, 0, stream>>>(X, Xb, Wq, Wk, Wv, Wo, Wqt, Wkt, Wvt, Wot,
                                 (int)(szE / 8));
  // fused QKV: M=8192 (32 by), N=6144 (24 bx); XCD supertile 12bx x 8by
  gemm256<0><<<768, 1024, 0, stream>>>(Xb, Wqt, bq, bk, bv, Qb, Vtp,
                                       Mn, 3 * En, En, 12, 8);
  attn<<<512, 512, 0, stream>>>(Qb, Kb, Vtp, AO);
  // output projection: M=8192 (32 by), N=2048 (8 bx); supertile 4bx x 8by
  gemm256<1><<<256, 1024, 0, stream>>>(AO, Wot, bo, nullptr, nullptr, d_out, nullptr,
                                       Mn, En, En, 4, 8);
}

// Round 16
// 454.377 us; speedup vs baseline: 1.0371x; 1.0371x over previous
//
#include <hip/hip_runtime.h>
#include <hip/hip_bf16.h>
#include <stdint.h>

typedef __bf16 bf16;
typedef float f32x4 __attribute__((ext_vector_type(4)));
typedef bf16 bf16x4 __attribute__((ext_vector_type(4)));
typedef bf16 bf16x8 __attribute__((ext_vector_type(8)));

#define DEV __device__ __forceinline__

DEV void gload16(const void* g, void* l) {
  __builtin_amdgcn_global_load_lds((const __attribute__((address_space(1))) void*)g,
                                   (__attribute__((address_space(3))) void*)l, 16, 0, 0);
}

DEV f32x4 mfma16(bf16x8 a, bf16x8 b, f32x4 c) {
  return __builtin_amdgcn_mfma_f32_16x16x32_bf16(a, b, c, 0, 0, 0);
}

#if __has_builtin(__builtin_amdgcn_exp2f)
DEV float EXP2F(float x) { return __builtin_amdgcn_exp2f(x); }
#else
DEV float EXP2F(float x) { return exp2f(x); }
#endif

static constexpr int Bn = 4, Sn = 2048, Hn = 16, Dn = 128, En = 2048, Mn = 8192;

// ---------------- fused prep: X fp32->bf16 + 4x W transpose ----------------
__global__ void prep(const float* __restrict__ X, bf16* __restrict__ Xb,
                     const float* __restrict__ Wq, const float* __restrict__ Wk,
                     const float* __restrict__ Wv, const float* __restrict__ Wo,
                     bf16* __restrict__ Wqt, bf16* __restrict__ Wkt,
                     bf16* __restrict__ Wvt, bf16* __restrict__ Wot, int n8) {
  __shared__ bf16 t[64][65];
  const int bid = blockIdx.x;
  if (bid < 2048) {
    int i = bid * 256 + threadIdx.x;
    const int stride = 2048 * 256;
    for (int idx = i; idx < n8; idx += stride) {
      const float4* p = (const float4*)(X + (size_t)idx * 8);
      float4 a = p[0], b = p[1];
      bf16x8 o;
      o[0]=(bf16)a.x; o[1]=(bf16)a.y; o[2]=(bf16)a.z; o[3]=(bf16)a.w;
      o[4]=(bf16)b.x; o[5]=(bf16)b.y; o[6]=(bf16)b.z; o[7]=(bf16)b.w;
      *(bf16x8*)(Xb + (size_t)idx * 8) = o;
    }
    return;
  }
  const int q = bid - 2048;
  const int mtx = q >> 10, within = q & 1023;
  const float* W = (mtx == 0) ? Wq : (mtx == 1) ? Wk : (mtx == 2) ? Wv : Wo;
  bf16* Wt = (mtx == 0) ? Wqt : (mtx == 1) ? Wkt : (mtx == 2) ? Wvt : Wot;
  int tx = threadIdx.x & 15, ty = threadIdx.x >> 4;
  int c0 = (within & 31) * 64, r0 = (within >> 5) * 64;
  #pragma unroll
  for (int i = 0; i < 4; ++i) {
    int r = i * 16 + ty;
    float4 v = *(const float4*)&W[(size_t)(r0 + r) * En + c0 + tx * 4];
    t[r][tx*4+0] = (bf16)v.x; t[r][tx*4+1] = (bf16)v.y;
    t[r][tx*4+2] = (bf16)v.z; t[r][tx*4+3] = (bf16)v.w;
  }
  __syncthreads();
  #pragma unroll
  for (int i = 0; i < 4; ++i) {
    int c = i * 16 + ty;
    bf16x4 o;
    #pragma unroll
    for (int j = 0; j < 4; ++j) o[j] = t[tx*4+j][c];
    *(bf16x4*)&Wt[(size_t)(c0 + c) * En + r0 + tx * 4] = o;
  }
}

// ---------------- 256x256 GEMM, 16 waves (r16 = exact r12 revert) ---------
// Best verified configuration: 189us QKV / 456us total (r12; reconfirmed as
// r14 baseline). BK=64 double-buffer, single-barrier slip loop, 2D-XCD
// supertiling, 0 bank conflicts, VGPR 64, occupancy 40%. Five schedule
// levers on this structure tested null/regressive (r9/r10/r14/r15) — the
// residual is LDS-read volume (256KB/tile > MFMA time), which register-
// blocking cannot cut without spilling (r13). Practical plateau.
#define STAGE_A(H, DBUF, KTN) do { \
    const bf16* s_ = A + (size_t)(mbase + (tid >> 2)) * K + (KTN) * 64 + (H) * 32 \
                     + (((tid & 3) ^ ((tid >> 3) & 3)) * 8); \
    gload16(s_, (DBUF) + (H) * 16384 + (w << 10)); \
  } while (0)
#define STAGE_B(H, DBUF, KTN) do { \
    const bf16* s_ = Bt + (size_t)(nbase + (tid >> 2)) * K + (KTN) * 64 + (H) * 32 \
                     + (((tid & 3) ^ ((tid >> 3) & 3)) * 8); \
    gload16(s_, (DBUF) + (H) * 16384 + (w << 10)); \
  } while (0)

template<int OUT_MODE>
__global__ __launch_bounds__(1024, 2) void gemm256(
    const bf16* __restrict__ A, const bf16* __restrict__ Bt,
    const float* __restrict__ b0, const float* __restrict__ b1,
    const float* __restrict__ b2, void* __restrict__ Cout,
    bf16* __restrict__ Vout,
    int M, int N, int K, int sbx, int sby)
{
  __shared__ __align__(16) uint8_t smem[131072];
  const int tid = threadIdx.x, lane = tid & 63, w = tid >> 6;   // w in [0,16)
  const int wm = w >> 2, wn = w & 3;                            // 4M x 4N waves
  const int g = lane >> 4, lr = lane & 15;
  const int gx = (g ^ ((lr >> 1) & 3)) << 4;   // swizzled 16B-chunk offset
  // 2D XCD super-tiling (r10)
  const int lid = blockIdx.x;
  const int xcd = lid & 7, i = lid >> 3;
  const int bx = (xcd & 1) * sbx + (i % sbx);
  const int by = (xcd >> 1) * sby + (i / sbx);
  const int mbase = by * 256, nbase = bx * 256;

  f32x4 acc[4][4] = {};

  // prologue: stage tile 0 fully (4 ops/thread), drain, join
  STAGE_A(0, smem, 0);
  STAGE_B(0, smem + 65536, 0);
  STAGE_A(1, smem, 0);
  STAGE_B(1, smem + 65536, 0);
  asm volatile("s_waitcnt vmcnt(0)" ::: "memory");
  __builtin_amdgcn_s_barrier();

  const int NKT = K >> 6;
  for (int kt = 0; kt < NKT; ++kt) {
    const int cur = kt & 1;
    uint8_t* Acur = smem + (cur << 15);
    uint8_t* Bcur = smem + 65536 + (cur << 15);
    uint8_t* Anxt = smem + ((cur ^ 1) << 15);
    uint8_t* Bnxt = smem + 65536 + ((cur ^ 1) << 15);
    const bool notlast = (kt + 1 < NKT);

    // issue next-tile staging first (max latency slack; 4 ops/thread)
    if (notlast) {
      STAGE_A(0, Anxt, kt + 1);
      STAGE_B(0, Bnxt, kt + 1);
      STAGE_A(1, Anxt, kt + 1);
      STAGE_B(1, Bnxt, kt + 1);
    }

    // per-K-half: read frags, MFMA (compiler emits fine-grained lgkmcnt)
    #pragma unroll
    for (int kh = 0; kh < 2; ++kh) {
      bf16x8 af[4], bfv[4];
      #pragma unroll
      for (int mf = 0; mf < 4; ++mf)
        af[mf] = *(const bf16x8*)(Acur + kh * 16384 + (wm * 64 + mf * 16 + lr) * 64 + gx);
      #pragma unroll
      for (int j = 0; j < 4; ++j)
        bfv[j] = *(const bf16x8*)(Bcur + kh * 16384 + (wn * 64 + j * 16 + lr) * 64 + gx);
      __builtin_amdgcn_s_setprio(1);
      #pragma unroll
      for (int mf = 0; mf < 4; ++mf)
        #pragma unroll
        for (int j = 0; j < 4; ++j)
          acc[mf][j] = mfma16(af[mf], bfv[j], acc[mf][j]);
      __builtin_amdgcn_s_setprio(0);
    }

    // retire own stage ops BEFORE the barrier (cross-wave invariant), join
    asm volatile("s_waitcnt vmcnt(0)" ::: "memory");
    __builtin_amdgcn_s_barrier();
  }

  // ---- epilogue (per-wave output block 64x64 at wm,wn) ----
  if constexpr (OUT_MODE == 0) {
    int tsel = nbase >> 11;
    if (tsel == 2) {
      #pragma unroll
      for (int j = 0; j < 4; ++j) {
        int nn = (nbase + wn * 64 + j * 16 + lr) & 2047;
        int h = nn >> 7, d = nn & 127;
        float bv = b2[nn];
        #pragma unroll
        for (int mf = 0; mf < 4; ++mf) {
          int m0 = mbase + wm * 64 + mf * 16 + g * 4;
          int b = m0 >> 11, s0 = m0 & 2047;
          bf16x4 o4;
          #pragma unroll
          for (int r = 0; r < 4; ++r) o4[r] = (bf16)(acc[mf][j][r] + bv);
          *(bf16x4*)&Vout[((size_t)(b * Hn + h) * Dn + d) * Sn + s0] = o4;
        }
      }
    } else {
      const float* bsel = (tsel == 0) ? b0 : b1;
      #pragma unroll
      for (int j = 0; j < 4; ++j) {
        int n = nbase + wn * 64 + j * 16 + lr;
        int nn = n & 2047;
        float bv = bsel[nn];
        int h = nn >> 7, d = nn & 127;
        #pragma unroll
        for (int mf = 0; mf < 4; ++mf) {
          #pragma unroll
          for (int r = 0; r < 4; ++r) {
            int m = mbase + wm * 64 + mf * 16 + g * 4 + r;
            int b = m >> 11, s = m & 2047;
            ((bf16*)Cout)[(size_t)tsel * ((size_t)Mn * En) +
                          ((size_t)(b * Hn + h) * Sn + s) * Dn + d] = (bf16)(acc[mf][j][r] + bv);
          }
        }
      }
    }
  } else {
    #pragma unroll
    for (int j = 0; j < 4; ++j) {
      int n = nbase + wn * 64 + j * 16 + lr;
      float bv = b0[n];
      #pragma unroll
      for (int mf = 0; mf < 4; ++mf) {
        #pragma unroll
        for (int r = 0; r < 4; ++r) {
          int m = mbase + wm * 64 + mf * 16 + g * 4 + r;
          ((float*)Cout)[(size_t)m * N + n] = acc[mf][j][r] + bv;
        }
      }
    }
  }
}

// ---------------- Flash attention (r9-identical, best-verified) ----------
__global__ __launch_bounds__(512, 2) void attn(
    const bf16* __restrict__ Q, const bf16* __restrict__ K,
    const bf16* __restrict__ Vt, bf16* __restrict__ O)
{
  __shared__ __align__(16) uint8_t smem[65536];
  const int tid = threadIdx.x, lane = tid & 63, w = tid >> 6;
  const int g = lane >> 4, lr = lane & 15;
  const int lid = blockIdx.x;
  const int xcd = lid & 7, j = lid >> 3;
  const int bh = xcd * 8 + (j >> 3);
  const int q0 = (j & 7) * 256;
  const size_t hoff = (size_t)bh * Sn * Dn;
  const bf16* Qh = Q + hoff;
  const bf16* Kh = K + hoff;
  const bf16* Vh = Vt + hoff;   // [D][S]
  const float SC2 = 0.12751744f; // 1/sqrt(128) * log2(e)

  #pragma unroll
  for (int it = 0; it < 8; ++it) {
    int cl = it * 512 + tid;
    int row = cl >> 4, cs = cl & 15;
    int cg = cs ^ (row & 7);
    gload16(Qh + (size_t)(q0 + row) * Dn + cg * 8, smem + (it * 512 + (tid & ~63)) * 16);
  }
  __syncthreads();
  bf16x8 qf[2][4];
  #pragma unroll
  for (int nf = 0; nf < 2; ++nf)
    #pragma unroll
    for (int ks = 0; ks < 4; ++ks) {
      int row = w * 32 + nf * 16 + lr;
      qf[nf][ks] = *(const bf16x8*)(smem + row * 256 + (((ks * 4 + g) ^ (row & 7)) << 4));
    }
  __syncthreads();

  const int vd = tid >> 2, vq = tid & 3;
  const bf16* vrow = Vh + (size_t)vd * Sn + (vq >> 1) * 32 + (vq & 1) * 8;

  uint4 u0, u1;
  #pragma unroll
  for (int it = 0; it < 2; ++it) {
    int cl = it * 512 + tid;
    int row = cl >> 4, cs = cl & 15;
    int cg = cs ^ (row & 7);
    gload16(Kh + (size_t)row * Dn + cg * 8, smem + (it * 512 + (tid & ~63)) * 16);
  }
  { const uint4* vs = (const uint4*)vrow; u0 = vs[0]; u1 = vs[2]; }

  f32x4 o[2][8] = {};
  float m2[2] = { -__builtin_inff(), -__builtin_inff() };
  float lrun[2] = { 0.f, 0.f };

  for (int t = 0; t < 32; ++t) {
    const int cur = t & 1;
    uint8_t* Kcur = smem + (cur << 14);
    uint8_t* Knxt = smem + ((cur ^ 1) << 14);
    uint8_t* Vcur = smem + 32768 + (cur << 14);
    asm volatile("s_waitcnt vmcnt(0)" ::: "memory");
    {
      uint8_t* base = Vcur + vd * 128;
      const int sw = vd & 7;
      *(uint4*)(base + (((2 * vq + 0) ^ sw) << 4)) = make_uint4(u0.x, u0.y, u1.x, u1.y);
      *(uint4*)(base + (((2 * vq + 1) ^ sw) << 4)) = make_uint4(u0.z, u0.w, u1.z, u1.w);
    }
    if (t < 31) {
      const int kvn = (t + 1) * 64;
      #pragma unroll
      for (int it = 0; it < 2; ++it) {
        int cl = it * 512 + tid;
        int row = cl >> 4, cs = cl & 15;
        int cg = cs ^ (row & 7);
        gload16(Kh + (size_t)(kvn + row) * Dn + cg * 8,
                Knxt + (it * 512 + (tid & ~63)) * 16);
      }
      const uint4* vs = (const uint4*)(vrow + kvn);
      u0 = vs[0]; u1 = vs[2];
    }
    asm volatile("s_waitcnt lgkmcnt(0)" ::: "memory");
    asm volatile("s_barrier" ::: "memory");

    f32x4 sfr[2][4] = {};
    __builtin_amdgcn_s_setprio(1);
    #pragma unroll
    for (int ks = 0; ks < 4; ++ks) {
      #pragma unroll
      for (int mf = 0; mf < 4; ++mf) {
        int row = mf * 16 + lr;
        bf16x8 kf = *(const bf16x8*)(Kcur + row * 256 + (((ks * 4 + g) ^ (row & 7)) << 4));
        sfr[0][mf] = mfma16(kf, qf[0][ks], sfr[0][mf]);
        sfr[1][mf] = mfma16(kf, qf[1][ks], sfr[1][mf]);
      }
    }
    __builtin_amdgcn_s_setprio(0);

    bf16x8 pa[2][2];
    #pragma unroll
    for (int nf = 0; nf < 2; ++nf) {
      f32x4 a0, a1;
      #pragma unroll
      for (int r = 0; r < 4; ++r) a0[r] = fmaxf(sfr[nf][0][r], sfr[nf][1][r]);
      #pragma unroll
      for (int r = 0; r < 4; ++r) a1[r] = fmaxf(sfr[nf][2][r], sfr[nf][3][r]);
      #pragma unroll
      for (int r = 0; r < 4; ++r) a0[r] = fmaxf(a0[r], a1[r]);
      float mx = fmaxf(fmaxf(a0[0], a0[1]), fmaxf(a0[2], a0[3]));
      mx = fmaxf(mx, __shfl_xor(mx, 16));
      mx = fmaxf(mx, __shfl_xor(mx, 32));
      float pm2 = mx * SC2;
      if (__any(pm2 > m2[nf] + 8.f)) {
        float mnew = fmaxf(m2[nf], pm2);
        float fsc = EXP2F(m2[nf] - mnew);
        m2[nf] = mnew;
        lrun[nf] *= fsc;
        float fv[4];
        #pragma unroll
        for (int r = 0; r < 4; ++r) fv[r] = __shfl(fsc, g * 4 + r);
        #pragma unroll
        for (int df = 0; df < 8; ++df)
          #pragma unroll
          for (int r = 0; r < 4; ++r) o[nf][df][r] *= fv[r];
      }
      const float mc = m2[nf];
      f32x4 p[4];
      #pragma unroll
      for (int mf = 0; mf < 4; ++mf)
        #pragma unroll
        for (int r = 0; r < 4; ++r)
          p[mf][r] = EXP2F(__builtin_fmaf(sfr[nf][mf][r], SC2, -mc));
      f32x4 s0, s1;
      #pragma unroll
      for (int r = 0; r < 4; ++r) s0[r] = p[0][r] + p[1][r];
      #pragma unroll
      for (int r = 0; r < 4; ++r) s1[r] = p[2][r] + p[3][r];
      #pragma unroll
      for (int r = 0; r < 4; ++r) s0[r] += s1[r];
      float ps = (s0[0] + s0[1]) + (s0[2] + s0[3]);
      ps += __shfl_xor(ps, 16);
      ps += __shfl_xor(ps, 32);
      lrun[nf] += ps;
      #pragma unroll
      for (int ks = 0; ks < 2; ++ks) {
        bf16x8 tt;
        #pragma unroll
        for (int i = 0; i < 4; ++i) {
          tt[i]     = (bf16)p[2 * ks][i];
          tt[i + 4] = (bf16)p[2 * ks + 1][i];
        }
        pa[nf][ks] = tt;
      }
    }

    __builtin_amdgcn_s_setprio(1);
    #pragma unroll
    for (int ks = 0; ks < 2; ++ks) {
      #pragma unroll
      for (int df = 0; df < 8; ++df) {
        int row = df * 16 + lr;
        bf16x8 vf = *(const bf16x8*)(Vcur + row * 128 + (((ks * 4 + g) ^ (row & 7)) << 4));
        o[0][df] = mfma16(pa[0][ks], vf, o[0][df]);
        o[1][df] = mfma16(pa[1][ks], vf, o[1][df]);
      }
    }
    __builtin_amdgcn_s_setprio(0);
    asm volatile("s_barrier" ::: "memory");
  }

  const int b = bh >> 4, h = bh & 15;
  #pragma unroll
  for (int nf = 0; nf < 2; ++nf) {
    float inv = 1.f / lrun[nf];
    float iv[4];
    #pragma unroll
    for (int r = 0; r < 4; ++r) iv[r] = __shfl(inv, g * 4 + r);
    #pragma unroll
    for (int df = 0; df < 8; ++df) {
      #pragma unroll
      for (int r = 0; r < 4; ++r) {
        int qrow = q0 + w * 32 + nf * 16 + g * 4 + r;
        int d = df * 16 + lr;
        size_t m = (size_t)b * Sn + qrow;
        O[m * En + h * Dn + d] = (bf16)(o[nf][df][r] * iv[r]);
      }
    }
  }
}

// ---------------- host ----------------
extern "C" void kernel_launch(void* const* d_in, const int* in_sizes, int n_in,
                              void* d_out, int out_size, void* d_ws, size_t ws_size,
                              hipStream_t stream) {
  const float* X  = (const float*)d_in[0];
  const float* Wq = (const float*)d_in[1];
  const float* bq = (const float*)d_in[2];
  const float* Wk = (const float*)d_in[3];
  const float* bk = (const float*)d_in[4];
  const float* Wv = (const float*)d_in[5];
  const float* bv = (const float*)d_in[6];
  const float* Wo = (const float*)d_in[7];
  const float* bo = (const float*)d_in[8];

  bf16* ws = (bf16*)d_ws;
  const size_t szE = (size_t)Mn * En;
  const size_t szW = (size_t)En * En;
  bf16* Xb  = ws;
  bf16* Wqt = Xb + szE;      // Wqt/Wkt/Wvt contiguous => fused QKV B-matrix [6144][2048]
  bf16* Wkt = Wqt + szW;
  bf16* Wvt = Wkt + szW;
  bf16* Wot = Wvt + szW;
  bf16* Qb  = Wot + szW;     // Q/K contiguous for tsel addressing
  bf16* Kb  = Qb + szE;
  bf16* Vb  = Kb + szE;      // region reused for AO
  bf16* Vtp = Vb + szE;      // V written directly transposed [bh][D][S]
  bf16* AO  = Vb;

  prep<<<6144, 256, 0, stream>>>(X, Xb, Wq, Wk, Wv, Wo, Wqt, Wkt, Wvt, Wot,
                                 (int)(szE / 8));
  // fused QKV: M=8192 (32 by), N=6144 (24 bx); XCD supertile 12bx x 8by
  gemm256<0><<<768, 1024, 0, stream>>>(Xb, Wqt, bq, bk, bv, Qb, Vtp,
                                       Mn, 3 * En, En, 12, 8);
  attn<<<512, 512, 0, stream>>>(Qb, Kb, Vtp, AO);
  // output projection: M=8192 (32 by), N=2048 (8 bx); supertile 4bx x 8by
  gemm256<1><<<256, 1024, 0, stream>>>(AO, Wot, bo, nullptr, nullptr, d_out, nullptr,
                                       Mn, En, En, 4, 8);
}